// Round 2
// baseline (494.627 us; speedup 1.0000x reference)
//
#include <hip/hip_runtime.h>
#include <stdint.h>

// SCC (sliding-channel conv) = 8 dense group-GEMMs (o%8==g reads channel band
// [128g,128g+256) mod 1024). bf16 MFMA 16x16x32.
// R4: persistent blocks + R2-replica LDS geometry.
//   - Grid = (64, 8) = 512 blocks = exactly 2/CU (LDS-capped). Each block
//     stages its g's W slice ONCE (64 KB bf16 LDS), one barrier total, then
//     grid-strides over all 784 (px, b) tiles.
//   - W image pre-packed by prologue kernel into d_ws using the R2 layout
//     that measured ZERO bank conflicts: 4 chunks x 16 KB, rows of 128 B,
//     8 x 16 B segments XOR-swizzled by (m&7). (R3's 512 B-row layout
//     measured 6.4M conflict cycles/dispatch.)
//   - k-loop is barrier-free and software-pipelined ACROSS tiles:
//     phase A computes kb0..3 while prefetching kb4..7 (bvB);
//     phase B computes kb4..7 while prefetching next tile's kb0..3 (bvA).
//     Loads stay in flight permanently; nothing drains vmcnt.

#define B_      16
#define C_IN    1024
#define C_OUT   1024
#define UNIT    256
#define STRIDE_ 128
#define HW      3136
#define NT      64              // spatial tile: 3136 = 49*64 exact
#define NTILES  (49 * B_)       // 784 (px, b) tiles per g
#define ZBLK    64              // persistent blocks per g

typedef __attribute__((ext_vector_type(8))) short bf16x8;
typedef __attribute__((ext_vector_type(4))) float floatx4;
typedef __attribute__((ext_vector_type(4))) short short4v;

__device__ __forceinline__ short f2bf(float f) {
    // fp32 -> bf16, round-to-nearest-even
    uint32_t u = __float_as_uint(f);
    u += 0x7FFFu + ((u >> 16) & 1u);
    return (short)(u >> 16);
}

// ---- prologue: W [1024][256] fp32 -> d_ws, 8 x 64KB swizzled bf16 images.
// Image g: 4 chunks of 16 KB (chunk c = k in [64c, 64c+64)); within a chunk,
// row m (o = g+8m) is 128 B = 8 segments of 16 B; segment s stored at slot
// (s ^ (m&7)).  This replicates the R2 LDS geometry (0 bank conflicts).
__global__ __launch_bounds__(256) void w_pack_kernel(
    const float* __restrict__ w, short* __restrict__ wp)
{
    int t   = blockIdx.x * 256 + threadIdx.x;   // 65536 threads x 4 floats
    int o   = t >> 6;                           // 0..1023
    int kk4 = (t & 63) << 2;                    // 0..252
    int g = o & 7, m = o >> 3;
    float4 v = *(const float4*)(w + ((size_t)o << 8) + kk4);
    short4v s4 = { f2bf(v.x), f2bf(v.y), f2bf(v.z), f2bf(v.w) };
    int c   = kk4 >> 6;                         // chunk 0..3
    int seg = (kk4 >> 3) & 7;                   // segment within chunk row
    char* dst = (char*)wp + ((size_t)g << 16) + (c << 14) + (m << 7)
              + (((seg ^ (m & 7)) << 4) | ((kk4 & 4) << 1));
    *(short4v*)dst = s4;
}

template <bool PRE>
__global__ __launch_bounds__(256, 2) void scc_mfma_kernel(
    const float* __restrict__ x, const float* __restrict__ w,
    const short* __restrict__ wp, float* __restrict__ out)
{
    __shared__ short Ws[128 * 256];  // 64 KB bf16: 4 chunks x (128 rows x 128 B)

    const int tid  = threadIdx.x;
    const int lane = tid & 63;
    const int wn   = tid >> 6;       // wave = one 16-wide N strip
    const int nq   = lane & 15;      // MFMA n-col / A-row index
    const int quad = lane >> 4;      // MFMA k-group

    const int z = blockIdx.x;        // persistent block slot 0..63
    const int g = blockIdx.y;

    char* wsb = (char*)Ws;

    // ---- prologue prefetch: first tile's kb0..3 into bvA (issued before the
    // W staging so HBM latency hides under it; the barrier drains vmcnt once
    // per block lifetime, which is amortized over ~12 tiles).
    float bvA[4][8], bvB[4][8];
    {
        int t0 = z;                          // z < 64 < NTILES always
        int b  = t0 / 49, px = t0 - b * 49;
        const float* xb = x + (size_t)b * C_IN * HW + px * NT + wn * 16 + nq;
#pragma unroll
        for (int kb = 0; kb < 4; ++kb) {
            int cb = (g * STRIDE_ + kb * 32 + quad * 8) & (C_IN - 1);
            const float* xp = xb + (size_t)cb * HW;
#pragma unroll
            for (int j = 0; j < 8; ++j) bvA[kb][j] = xp[(size_t)j * HW];
        }
    }

    // ---- stage the whole W slice once per block lifetime
    if (PRE) {
        // pre-swizzled bf16 image in workspace: plain linear 64 KB copy
        const char* wsrc = (const char*)(wp + (size_t)g * 32768);
#pragma unroll
        for (int i = 0; i < 16; ++i) {
            int4 v = *(const int4*)(wsrc + i * 4096 + tid * 16);
            *(int4*)(wsb + i * 4096 + tid * 16) = v;
        }
    } else {
        // fallback: convert fp32 W in-kernel (ws too small), same layout
#pragma unroll
        for (int r = 0; r < 32; ++r) {
            int f   = tid + 256 * r;          // 0..8191 float4s
            int m   = f >> 6;                 // 0..127
            int kk4 = (f & 63) << 2;          // 0..252
            float4 v = *(const float4*)(w + (size_t)(g + 8 * m) * UNIT + kk4);
            short4v s4 = { f2bf(v.x), f2bf(v.y), f2bf(v.z), f2bf(v.w) };
            int c   = kk4 >> 6;
            int seg = (kk4 >> 3) & 7;
            *(short4v*)(wsb + (c << 14) + (m << 7)
                        + (((seg ^ (m & 7)) << 4) | ((kk4 & 4) << 1))) = s4;
        }
    }

    __syncthreads();   // the ONLY barrier in the block's lifetime

    // ---- persistent tile loop: block handles tiles z, z+64, ... (<784)
    for (int t = z; t < NTILES; t += ZBLK) {
        int b  = t / 49, px = t - b * 49;
        const float* xb = x + (size_t)b * C_IN * HW + px * NT + wn * 16 + nq;
        int tn = t + ZBLK;
        int bn = tn / 49, pxn = tn - bn * 49;          // may be OOB; guarded
        const float* xbn = x + (size_t)bn * C_IN * HW + pxn * NT + wn * 16 + nq;

        floatx4 acc[8];
#pragma unroll
        for (int i = 0; i < 8; ++i) acc[i] = (floatx4){0.f, 0.f, 0.f, 0.f};

        // phase A: compute kb 0..3 from bvA; prefetch this tile's kb 4..7
        #pragma unroll
        for (int kb = 0; kb < 4; ++kb) {
            {
                int cb = (g * STRIDE_ + (kb + 4) * 32 + quad * 8) & (C_IN - 1);
                const float* xp = xb + (size_t)cb * HW;
#pragma unroll
                for (int j = 0; j < 8; ++j) bvB[kb][j] = xp[(size_t)j * HW];
            }
            bf16x8 bfrag;
#pragma unroll
            for (int j = 0; j < 8; ++j) bfrag[j] = f2bf(bvA[kb][j]);
            const int aoff = (kb >> 1) * 16384 + nq * 128
                           + ((((kb & 1) * 4 + quad) ^ (nq & 7)) << 4);
#pragma unroll
            for (int mf = 0; mf < 8; ++mf) {
                bf16x8 afrag = *(const bf16x8*)(wsb + mf * 2048 + aoff);
                acc[mf] = __builtin_amdgcn_mfma_f32_16x16x32_bf16(afrag, bfrag, acc[mf], 0, 0, 0);
            }
        }
        // phase B: compute kb 4..7 from bvB; prefetch NEXT tile's kb 0..3
        #pragma unroll
        for (int kb = 0; kb < 4; ++kb) {
            if (tn < NTILES) {
                int cb = (g * STRIDE_ + kb * 32 + quad * 8) & (C_IN - 1);
                const float* xp = xbn + (size_t)cb * HW;
#pragma unroll
                for (int j = 0; j < 8; ++j) bvA[kb][j] = xp[(size_t)j * HW];
            }
            bf16x8 bfrag;
#pragma unroll
            for (int j = 0; j < 8; ++j) bfrag[j] = f2bf(bvB[kb][j]);
            const int kk = kb + 4;
            const int aoff = (kk >> 1) * 16384 + nq * 128
                           + ((((kk & 1) * 4 + quad) ^ (nq & 7)) << 4);
#pragma unroll
            for (int mf = 0; mf < 8; ++mf) {
                bf16x8 afrag = *(const bf16x8*)(wsb + mf * 2048 + aoff);
                acc[mf] = __builtin_amdgcn_mfma_f32_16x16x32_bf16(afrag, bfrag, acc[mf], 0, 0, 0);
            }
        }

        // epilogue: D col = nq (=p), row = quad*4 + reg within each 16-block;
        // o = g + 8*(mf*16 + quad*4 + reg) = g + 128*mf + 32*quad + 8*reg
        float* ob = out + ((size_t)b * C_OUT + g + 32 * quad) * HW
                  + px * NT + wn * 16 + nq;
#pragma unroll
        for (int mf = 0; mf < 8; ++mf) {
            float* o2 = ob + (size_t)(128 * mf) * HW;
#pragma unroll
            for (int reg = 0; reg < 4; ++reg)
                o2[(size_t)(8 * reg) * HW] = acc[mf][reg];
        }
    }
}

extern "C" void kernel_launch(void* const* d_in, const int* in_sizes, int n_in,
                              void* d_out, int out_size, void* d_ws, size_t ws_size,
                              hipStream_t stream)
{
    const float* x = (const float*)d_in[0];
    const float* w = (const float*)d_in[1];
    float* out = (float*)d_out;

    dim3 grid(ZBLK, 8);   // (64, 8) = 512 blocks = 2/CU on 256 CUs
    if (d_ws && ws_size >= (size_t)524288) {
        short* wp = (short*)d_ws;
        w_pack_kernel<<<dim3(256), 256, 0, stream>>>(w, wp);
        scc_mfma_kernel<true><<<grid, 256, 0, stream>>>(x, w, wp, out);
    } else {
        scc_mfma_kernel<false><<<grid, 256, 0, stream>>>(x, w, (const short*)nullptr, out);
    }
}

// Round 3
// 409.058 us; speedup vs baseline: 1.2092x; 1.2092x over previous
//
#include <hip/hip_runtime.h>
#include <stdint.h>

// SCC (sliding-channel conv) = 8 dense group-GEMMs (o%8==g reads channel band
// [128g,128g+256) mod 1024). bf16 MFMA 16x16x32.
// R5: non-persistent grid (R3's dispatch order gave perfect x dedup: FETCH
// 218 MB; R4's persistence broke it: 531 MB) + M-split blocks for occupancy.
//   - Block = M64 x N64, full K=256: W slice 32 KB LDS -> 4 blocks/CU
//     (was 64 KB -> 2/CU). Doubled latency cover is the point.
//   - M-split partner blocks adjacent in dispatch (bx = px*2 + mh) so their
//     shared x tile dedups in L2/LLC like the g-pairs do.
//   - W pre-packed by prologue kernel into d_ws in the chunked layout that
//     measured ZERO bank conflicts (R4): 4 chunks (K64) x 64 rows x 128 B,
//     8 x 16 B segments XOR-swizzled by (m&7).
//   - One barrier per block; prologue x prefetch before staging; k-loop
//     2-phase pipelined (kb<4 prefetches kb+4), barrier-free.

#define B_      16
#define C_IN    1024
#define C_OUT   1024
#define UNIT    256
#define STRIDE_ 128
#define HW      3136
#define NT      64      // spatial tile: 3136 = 49*64 exact

typedef __attribute__((ext_vector_type(8))) short bf16x8;
typedef __attribute__((ext_vector_type(4))) float floatx4;
typedef __attribute__((ext_vector_type(4))) short short4v;

__device__ __forceinline__ short f2bf(float f) {
    // fp32 -> bf16, round-to-nearest-even
    uint32_t u = __float_as_uint(f);
    u += 0x7FFFu + ((u >> 16) & 1u);
    return (short)(u >> 16);
}

// ---- prologue: W [1024][256] fp32 -> d_ws, 16 x 32KB swizzled bf16 images
// (one per (g, mh)). Image (g,mh): 4 chunks of 8 KB (chunk c = k in
// [64c, 64c+64)); within a chunk, row m (o = g + 8*(mh*64+m)) is 128 B =
// 8 segments of 16 B; segment s stored at slot (s ^ (m&7)).
__global__ __launch_bounds__(256) void w_pack_kernel(
    const float* __restrict__ w, short* __restrict__ wp)
{
    int t   = blockIdx.x * 256 + threadIdx.x;   // 65536 threads x 4 floats
    int o   = t >> 6;                           // 0..1023
    int kk4 = (t & 63) << 2;                    // 0..252
    int g = o & 7, mg = o >> 3;                 // mg 0..127
    int mh = mg >> 6, m = mg & 63;
    float4 v = *(const float4*)(w + ((size_t)o << 8) + kk4);
    short4v s4 = { f2bf(v.x), f2bf(v.y), f2bf(v.z), f2bf(v.w) };
    int c   = kk4 >> 6;                         // chunk 0..3
    int seg = (kk4 >> 3) & 7;                   // 16B segment within chunk row
    char* dst = (char*)wp + ((size_t)(g * 2 + mh) << 15) + (c << 13) + (m << 7)
              + (((seg ^ (m & 7)) << 4) | ((kk4 & 4) << 1));
    *(short4v*)dst = s4;
}

template <bool PRE>
__global__ __launch_bounds__(256, 4) void scc_mfma_kernel(
    const float* __restrict__ x, const float* __restrict__ w,
    const short* __restrict__ wp, float* __restrict__ out)
{
    __shared__ short Ws[64 * 256];   // 32 KB bf16: 4 chunks x (64 rows x 128 B)

    const int tid  = threadIdx.x;
    const int lane = tid & 63;
    const int wn   = tid >> 6;       // wave = one 16-wide N strip
    const int nq   = lane & 15;      // MFMA n-col / A-row index
    const int quad = lane >> 4;      // MFMA k-group

    const int bx = blockIdx.x;
    const int px = bx >> 1;          // spatial tile 0..48
    const int mh = bx & 1;           // M half 0..1 (partners adjacent in dispatch)
    const int g  = blockIdx.y;
    const int b  = blockIdx.z;

    const int    p  = px * NT + wn * 16 + nq;
    const float* xb = x + (size_t)b * C_IN * HW + p;

    // ---- issue x loads for kb=0..3 FIRST: their HBM latency hides under
    // the W staging + the single barrier below.
    float bv[8][8];
#pragma unroll
    for (int kb = 0; kb < 4; ++kb) {
        int cb = (g * STRIDE_ + kb * 32 + quad * 8) & (C_IN - 1);
        const float* xp = xb + (size_t)cb * HW;
#pragma unroll
        for (int j = 0; j < 8; ++j) bv[kb][j] = xp[(size_t)j * HW];
    }

    // ---- stage this block's 32 KB W slice once
    char* wsb = (char*)Ws;
    if (PRE) {
        // pre-swizzled bf16 image in workspace: plain linear 32 KB copy
        const char* wsrc = (const char*)wp + ((size_t)(g * 2 + mh) << 15);
#pragma unroll
        for (int i = 0; i < 8; ++i) {
            int4 v = *(const int4*)(wsrc + i * 4096 + tid * 16);
            *(int4*)(wsb + i * 4096 + tid * 16) = v;
        }
    } else {
        // fallback: convert fp32 W in-kernel (ws too small), same layout
#pragma unroll
        for (int r = 0; r < 16; ++r) {
            int f   = tid + 256 * r;          // 0..4095 float4s
            int m   = f >> 6;                 // 0..63
            int kk4 = (f & 63) << 2;          // 0..252
            float4 v = *(const float4*)(w + (size_t)(g + 8 * (mh * 64 + m)) * UNIT + kk4);
            short4v s4 = { f2bf(v.x), f2bf(v.y), f2bf(v.z), f2bf(v.w) };
            int c   = kk4 >> 6;
            int seg = (kk4 >> 3) & 7;
            *(short4v*)(wsb + (c << 13) + (m << 7)
                        + (((seg ^ (m & 7)) << 4) | ((kk4 & 4) << 1))) = s4;
        }
    }

    floatx4 acc[4];
#pragma unroll
    for (int i = 0; i < 4; ++i) acc[i] = (floatx4){0.f, 0.f, 0.f, 0.f};

    __syncthreads();   // the ONLY barrier: Ws valid, bv[0..3] resident

    // ---- barrier-free k-loop: 8 k-steps of 32; prefetch kb+4 while
    // computing kb (loads stay outstanding across iterations).
#pragma unroll
    for (int kb = 0; kb < 8; ++kb) {
        if (kb < 4) {
            int cb = (g * STRIDE_ + (kb + 4) * 32 + quad * 8) & (C_IN - 1);
            const float* xp = xb + (size_t)cb * HW;
#pragma unroll
            for (int j = 0; j < 8; ++j) bv[kb + 4][j] = xp[(size_t)j * HW];
        }
        bf16x8 bfrag;
#pragma unroll
        for (int j = 0; j < 8; ++j) bfrag[j] = f2bf(bv[kb][j]);
        // chunk c = kb>>1 (8 KB each); row = mf*16+nq (128 B rows);
        // slot = ((kb&1)*4 + quad) ^ (nq&7)  -> 0 bank conflicts (measured)
        const int aoff = (kb >> 1) * 8192 + nq * 128
                       + ((((kb & 1) * 4 + quad) ^ (nq & 7)) << 4);
#pragma unroll
        for (int mf = 0; mf < 4; ++mf) {
            bf16x8 afrag = *(const bf16x8*)(wsb + mf * 2048 + aoff);
            acc[mf] = __builtin_amdgcn_mfma_f32_16x16x32_bf16(afrag, bfrag, acc[mf], 0, 0, 0);
        }
    }

    // ---- epilogue: D col = nq (=p), row = quad*4 + reg within each 16-block;
    // o = g + 8*(mh*64 + mf*16 + quad*4 + reg)
    //   = g + 512*mh + 128*mf + 32*quad + 8*reg
    float* ob = out + ((size_t)b * C_OUT + g + 512 * mh + 32 * quad) * HW + p;
#pragma unroll
    for (int mf = 0; mf < 4; ++mf) {
        float* o2 = ob + (size_t)(128 * mf) * HW;
#pragma unroll
        for (int reg = 0; reg < 4; ++reg)
            o2[(size_t)(8 * reg) * HW] = acc[mf][reg];
    }
}

extern "C" void kernel_launch(void* const* d_in, const int* in_sizes, int n_in,
                              void* d_out, int out_size, void* d_ws, size_t ws_size,
                              hipStream_t stream)
{
    const float* x = (const float*)d_in[0];
    const float* w = (const float*)d_in[1];
    float* out = (float*)d_out;

    dim3 grid(2 * (HW / NT), 8, B_);   // (98, 8, 16); bx = px*2 + mh
    if (d_ws && ws_size >= (size_t)524288) {
        short* wp = (short*)d_ws;
        w_pack_kernel<<<dim3(256), 256, 0, stream>>>(w, wp);
        scc_mfma_kernel<true><<<grid, 256, 0, stream>>>(x, w, wp, out);
    } else {
        scc_mfma_kernel<false><<<grid, 256, 0, stream>>>(x, w, (const short*)nullptr, out);
    }
}

// Round 4
// 348.924 us; speedup vs baseline: 1.4176x; 1.1723x over previous
//
#include <hip/hip_runtime.h>
#include <stdint.h>

// SCC (sliding-channel conv) = 8 dense group-GEMMs (o%8==g reads channel band
// [128g,128g+256) mod 1024). bf16 MFMA 16x16x32.
// R6 = R3 structure (best: 126us, FETCH 218MB = x once) + three fixes:
//   1. Zero-conflict chunked LDS layout (verified 0 in R4/R5 vs 6.4M cyc/disp
//      in R3): 4 chunks x 16KB, 128B rows, 16B slots XOR-swizzled by (m&7).
//   2. Counted-vmcnt raw barrier (T4): issue 16 W loads, then ALL 64 x loads,
//      then ds_writes (compiler waits vmcnt(63) = W done, 63 x still in
//      flight), then lgkmcnt(0) + raw s_barrier + sched_barrier(0).
//      x loads stream ACROSS the barrier -- no per-block pipeline restart
//      (__syncthreads would emit vmcnt(0) and drain everything).
//   3. XCD co-location: id = 64*(t/8) + 8*g + (t%8) puts all 8 g-blocks of a
//      spatial tile t on ONE XCD (id%8 = t%8 under round-robin dispatch), so
//      the g<->g+1 shared x read is a local-L2 hit (R5 showed cross-XCD
//      sharing does NOT dedup before HBM).
//   Block = M128 x N64 (full M -- R5 showed splitting M across blocks doubles
//   HBM fetch), K=256, 64KB LDS, 2 blocks/CU, one barrier per block lifetime.

#define B_      16
#define C_IN    1024
#define C_OUT   1024
#define UNIT    256
#define STRIDE_ 128
#define HW      3136
#define NT      64              // spatial tile: 3136 = 49*64 exact
#define NTILES  (49 * B_)       // 784 tiles = 98 * 8

typedef __attribute__((ext_vector_type(8))) short bf16x8;
typedef __attribute__((ext_vector_type(4))) float floatx4;
typedef __attribute__((ext_vector_type(4))) short short4v;

__device__ __forceinline__ short f2bf(float f) {
    // fp32 -> bf16, round-to-nearest-even
    uint32_t u = __float_as_uint(f);
    u += 0x7FFFu + ((u >> 16) & 1u);
    return (short)(u >> 16);
}

// ---- prologue: W [1024][256] fp32 -> d_ws, 8 x 64KB swizzled bf16 images.
// Image g: 4 chunks of 16 KB (chunk c = k in [64c,64c+64)); row m (o=g+8m)
// is 128 B = 8 x 16 B segments; segment s at slot (s ^ (m&7)).
// This layout measured ZERO bank conflicts (R4/R5).
__global__ __launch_bounds__(256) void w_pack_kernel(
    const float* __restrict__ w, short* __restrict__ wp)
{
    int t   = blockIdx.x * 256 + threadIdx.x;   // 65536 threads x 4 floats
    int o   = t >> 6;                           // 0..1023
    int kk4 = (t & 63) << 2;                    // 0..252
    int g = o & 7, m = o >> 3;
    float4 v = *(const float4*)(w + ((size_t)o << 8) + kk4);
    short4v s4 = { f2bf(v.x), f2bf(v.y), f2bf(v.z), f2bf(v.w) };
    int c   = kk4 >> 6;                         // chunk 0..3
    int seg = (kk4 >> 3) & 7;                   // 16B segment within chunk row
    char* dst = (char*)wp + ((size_t)g << 16) + (c << 14) + (m << 7)
              + (((seg ^ (m & 7)) << 4) | ((kk4 & 4) << 1));
    *(short4v*)dst = s4;
}

template <bool PRE>
__global__ __launch_bounds__(256, 2) void scc_mfma_kernel(
    const float* __restrict__ x, const float* __restrict__ w,
    const short* __restrict__ wp, float* __restrict__ out)
{
    __shared__ short Ws[128 * 256];  // 64 KB: 4 chunks x (128 rows x 128 B)

    const int tid  = threadIdx.x;
    const int lane = tid & 63;
    const int wn   = tid >> 6;       // wave = one 16-wide N strip
    const int nq   = lane & 15;      // MFMA n-col / A-row index
    const int quad = lane >> 4;      // MFMA k-group

    // XCD co-location decode: id = 64*(t/8) + 8*g + (t%8)
    const int id  = blockIdx.x;
    const int g   = (id >> 3) & 7;
    const int t   = ((id >> 6) << 3) + (id & 7);   // 0..783
    const int b   = t / 49;
    const int px  = t - b * 49;

    const int    p  = px * NT + wn * 16 + nq;
    const float* xb = x + (size_t)b * C_IN * HW + p;
    char* wsb = (char*)Ws;

    if (PRE) {
        // ---- 1. W staging loads FIRST (oldest in vmem queue)
        const char* wsrc = (const char*)wp + ((size_t)g << 16);
        int4 wtmp[16];
#pragma unroll
        for (int i = 0; i < 16; ++i)
            wtmp[i] = *(const int4*)(wsrc + i * 4096 + tid * 16);

        // ---- 2. ALL 64 x loads (stay in flight across the barrier)
        float bv[8][8];
#pragma unroll
        for (int kb = 0; kb < 8; ++kb) {
            int cb = (g * STRIDE_ + kb * 32 + quad * 8) & (C_IN - 1);
            const float* xp = xb + (size_t)cb * HW;
#pragma unroll
            for (int j = 0; j < 8; ++j) bv[kb][j] = xp[(size_t)j * HW];
        }

        // ---- 3. LDS writes (compiler emits counted vmcnt for wtmp only)
#pragma unroll
        for (int i = 0; i < 16; ++i)
            *(int4*)(wsb + i * 4096 + tid * 16) = wtmp[i];

        // ---- 4. raw barrier: lgkmcnt(0) only -- do NOT drain vmcnt
        asm volatile("s_waitcnt lgkmcnt(0)" ::: "memory");
        __builtin_amdgcn_s_barrier();
        __builtin_amdgcn_sched_barrier(0);

        floatx4 acc[8];
#pragma unroll
        for (int i = 0; i < 8; ++i) acc[i] = (floatx4){0.f, 0.f, 0.f, 0.f};

        // ---- 5. pure-consume k-loop: f2bf + ds_read + MFMA, zero loads
#pragma unroll
        for (int kb = 0; kb < 8; ++kb) {
            bf16x8 bfrag;
#pragma unroll
            for (int j = 0; j < 8; ++j) bfrag[j] = f2bf(bv[kb][j]);
            const int aoff = (kb >> 1) * 16384 + nq * 128
                           + ((((kb & 1) * 4 + quad) ^ (nq & 7)) << 4);
#pragma unroll
            for (int mf = 0; mf < 8; ++mf) {
                bf16x8 afrag = *(const bf16x8*)(wsb + mf * 2048 + aoff);
                acc[mf] = __builtin_amdgcn_mfma_f32_16x16x32_bf16(afrag, bfrag, acc[mf], 0, 0, 0);
            }
        }

        // ---- epilogue: o = g + 128*mf + 32*quad + 8*reg, col p
        float* ob = out + ((size_t)b * C_OUT + g + 32 * quad) * HW + p;
#pragma unroll
        for (int mf = 0; mf < 8; ++mf) {
            float* o2 = ob + (size_t)(128 * mf) * HW;
#pragma unroll
            for (int reg = 0; reg < 4; ++reg)
                o2[(size_t)(8 * reg) * HW] = acc[mf][reg];
        }
    } else {
        // ---- fallback (ws too small): in-kernel W convert, plain barrier
        float bv[8][8];
#pragma unroll
        for (int kb = 0; kb < 8; ++kb) {
            int cb = (g * STRIDE_ + kb * 32 + quad * 8) & (C_IN - 1);
            const float* xp = xb + (size_t)cb * HW;
#pragma unroll
            for (int j = 0; j < 8; ++j) bv[kb][j] = xp[(size_t)j * HW];
        }
#pragma unroll
        for (int r = 0; r < 32; ++r) {
            int f   = tid + 256 * r;          // 0..8191 float4s
            int m   = f >> 6;                 // 0..127
            int kk4 = (f & 63) << 2;          // 0..252
            float4 v = *(const float4*)(w + (size_t)(g + 8 * m) * UNIT + kk4);
            short4v s4 = { f2bf(v.x), f2bf(v.y), f2bf(v.z), f2bf(v.w) };
            int c   = kk4 >> 6;
            int seg = (kk4 >> 3) & 7;
            *(short4v*)(wsb + (c << 14) + (m << 7)
                        + (((seg ^ (m & 7)) << 4) | ((kk4 & 4) << 1))) = s4;
        }
        __syncthreads();

        floatx4 acc[8];
#pragma unroll
        for (int i = 0; i < 8; ++i) acc[i] = (floatx4){0.f, 0.f, 0.f, 0.f};
#pragma unroll
        for (int kb = 0; kb < 8; ++kb) {
            bf16x8 bfrag;
#pragma unroll
            for (int j = 0; j < 8; ++j) bfrag[j] = f2bf(bv[kb][j]);
            const int aoff = (kb >> 1) * 16384 + nq * 128
                           + ((((kb & 1) * 4 + quad) ^ (nq & 7)) << 4);
#pragma unroll
            for (int mf = 0; mf < 8; ++mf) {
                bf16x8 afrag = *(const bf16x8*)(wsb + mf * 2048 + aoff);
                acc[mf] = __builtin_amdgcn_mfma_f32_16x16x32_bf16(afrag, bfrag, acc[mf], 0, 0, 0);
            }
        }
        float* ob = out + ((size_t)b * C_OUT + g + 32 * quad) * HW + p;
#pragma unroll
        for (int mf = 0; mf < 8; ++mf) {
            float* o2 = ob + (size_t)(128 * mf) * HW;
#pragma unroll
            for (int reg = 0; reg < 4; ++reg)
                o2[(size_t)(8 * reg) * HW] = acc[mf][reg];
        }
    }
}

extern "C" void kernel_launch(void* const* d_in, const int* in_sizes, int n_in,
                              void* d_out, int out_size, void* d_ws, size_t ws_size,
                              hipStream_t stream)
{
    const float* x = (const float*)d_in[0];
    const float* w = (const float*)d_in[1];
    float* out = (float*)d_out;

    dim3 grid(NTILES * 8);   // 6272 blocks; id = 64*(t/8) + 8*g + (t%8)
    if (d_ws && ws_size >= (size_t)524288) {
        short* wp = (short*)d_ws;
        w_pack_kernel<<<dim3(256), 256, 0, stream>>>(w, wp);
        scc_mfma_kernel<true><<<grid, 256, 0, stream>>>(x, w, wp, out);
    } else {
        scc_mfma_kernel<false><<<grid, 256, 0, stream>>>(x, w, (const short*)nullptr, out);
    }
}